// Round 11
// baseline (77.899 us; speedup 1.0000x reference)
//
#include <hip/hip_runtime.h>
#include <math.h>

#define BB 8
#define NN 2048
#define FF 128
#define LALPHA 0.2f
#define CH 16
#define NCH (NN / CH)     // 128
#define GC 4              // chunks per emit block
#define NG (NCH / GC)     // 32 groups

// ---------------- K1: h = x @ W^T, si = h.a1, sj = h.a2 ----------------
// 256 blocks (1/CU) x 256 threads; 64 rows x 128 cols; thread tile 4x8.
// W in LDS; x read directly from global (L1-broadcast).
#define K1R 64
__global__ __launch_bounds__(256, 1)
void k1_h(const float* __restrict__ x, const float* __restrict__ W,
          const float* __restrict__ a, float* __restrict__ h,
          float* __restrict__ si, float* __restrict__ sj)
{
    __shared__ float Wt[FF * 132];
    const int t = threadIdx.x;
    const int row0 = blockIdx.x * K1R;

    for (int kk = t; kk < FF * FF; kk += 256) {
        int o = kk >> 7, f = kk & (FF - 1);
        Wt[f * 132 + o] = W[kk];
    }
    __syncthreads();

    const int tx = t & 15, ty = t >> 4;
    const int oq = tx << 3;
    const int rq = ty << 2;
    float acc[4][8];
#pragma unroll
    for (int r = 0; r < 4; ++r)
#pragma unroll
        for (int c = 0; c < 8; ++c) acc[r][c] = 0.f;

    for (int f0 = 0; f0 < FF; f0 += 4) {
        float4 xv[4];
#pragma unroll
        for (int r = 0; r < 4; ++r)
            xv[r] = *(const float4*)&x[(size_t)(row0 + rq + r) * FF + f0];
#pragma unroll
        for (int ff = 0; ff < 4; ++ff) {
            float4 w0 = *(const float4*)&Wt[(f0 + ff) * 132 + oq];
            float4 w1 = *(const float4*)&Wt[(f0 + ff) * 132 + oq + 4];
            const float wc[8] = {w0.x, w0.y, w0.z, w0.w, w1.x, w1.y, w1.z, w1.w};
#pragma unroll
            for (int r = 0; r < 4; ++r) {
                const float xr = (ff == 0) ? xv[r].x : (ff == 1) ? xv[r].y
                               : (ff == 2) ? xv[r].z : xv[r].w;
#pragma unroll
                for (int c = 0; c < 8; ++c)
                    acc[r][c] += xr * wc[c];
            }
        }
    }
#pragma unroll
    for (int r = 0; r < 4; ++r) {
        float* hp = &h[(size_t)(row0 + rq + r) * FF + oq];
        *(float4*)hp       = make_float4(acc[r][0], acc[r][1], acc[r][2], acc[r][3]);
        *(float4*)(hp + 4) = make_float4(acc[r][4], acc[r][5], acc[r][6], acc[r][7]);
    }
    const float4 a10 = *(const float4*)&a[oq];
    const float4 a11 = *(const float4*)&a[oq + 4];
    const float4 a20 = *(const float4*)&a[FF + oq];
    const float4 a21 = *(const float4*)&a[FF + oq + 4];
    const float a1v[8] = {a10.x, a10.y, a10.z, a10.w, a11.x, a11.y, a11.z, a11.w};
    const float a2v[8] = {a20.x, a20.y, a20.z, a20.w, a21.x, a21.y, a21.z, a21.w};
#pragma unroll
    for (int r = 0; r < 4; ++r) {
        float s1 = 0.f, s2 = 0.f;
#pragma unroll
        for (int c = 0; c < 8; ++c) { s1 += acc[r][c] * a1v[c]; s2 += acc[r][c] * a2v[c]; }
#pragma unroll
        for (int off = 8; off >= 1; off >>= 1) {
            s1 += __shfl_down(s1, off, 16);
            s2 += __shfl_down(s2, off, 16);
        }
        if (tx == 0) { si[row0 + rq + r] = s1; sj[row0 + rq + r] = s2; }
    }
}

// ---------------- K2: rank-sort sj per batch (+ exp weights) ----------------
// grid = B*32 = 256 blocks, 1024 threads; 16 slices per element.
__global__ __launch_bounds__(1024)
void k2_rank(const float* __restrict__ sj, float* __restrict__ keys, int* __restrict__ sidx,
             float* __restrict__ ew1, float* __restrict__ ew2)
{
    __shared__ float lk[NN];
    const int b = blockIdx.x >> 5;
    const int s = blockIdx.x & 31;
    const int t = threadIdx.x;
    for (int j = t; j < NN; j += 1024) lk[j] = sj[b * NN + j];
    __syncthreads();
    const int e = s * 64 + (t >> 4);
    const int slice = t & 15;
    const float ki = lk[e];
    const float4* lk4 = (const float4*)lk;
    int r = 0;
#pragma unroll 8
    for (int it = 0; it < 32; ++it) {
        int q = slice + (it << 4);
        float4 v = lk4[q];
        int j = q << 2;
        r += (v.x < ki || (v.x == ki && (j + 0) < e));
        r += (v.y < ki || (v.y == ki && (j + 1) < e));
        r += (v.z < ki || (v.z == ki && (j + 2) < e));
        r += (v.w < ki || (v.w == ki && (j + 3) < e));
    }
    r += __shfl_down(r, 8, 16);
    r += __shfl_down(r, 4, 16);
    r += __shfl_down(r, 2, 16);
    r += __shfl_down(r, 1, 16);
    if (slice == 0) {
        keys[b * NN + r] = ki;
        sidx[b * NN + r] = e;
        ew1[b * NN + r] = expf(ki);
        ew2[b * NN + r] = expf(LALPHA * ki);
    }
}

// ---------------- K3a: chunk sums only ----------------
// grid = B*NCH = 1024 blocks, 128 threads.
__global__ __launch_bounds__(128)
void k3a_csum(const float* __restrict__ h, const int* __restrict__ sidx,
              const float* __restrict__ ew1, const float* __restrict__ ew2,
              float* __restrict__ csum1, float* __restrict__ csum2,
              float* __restrict__ ssum1, float* __restrict__ ssum2)
{
    const int bid = blockIdx.x;
    const int b = bid >> 7, c = bid & (NCH - 1);
    const int o = threadIdx.x;
    const int m0 = c * CH;

    __shared__ float lw1[CH], lw2[CH];
    __shared__ int li[CH];
    if (o < CH) {
        lw1[o] = ew1[b * NN + m0 + o];
        lw2[o] = ew2[b * NN + m0 + o];
        li[o]  = sidx[b * NN + m0 + o];
    }
    __syncthreads();

    float r[CH];
#pragma unroll
    for (int m = 0; m < CH; ++m)
        r[m] = h[(size_t)(b * NN + li[m]) * FF + o];

    float a1 = 0.f, a2 = 0.f, s1 = 0.f, s2 = 0.f;
#pragma unroll
    for (int m = 0; m < CH; ++m) {
        float w1 = lw1[m], w2 = lw2[m];
        a1 += w1 * r[m]; a2 += w2 * r[m];
        s1 += w1;        s2 += w2;
    }
    csum1[(size_t)bid * FF + o] = a1;
    csum2[(size_t)bid * FF + o] = a2;
    if (o == 0) { ssum1[bid] = s1; ssum2[bid] = s2; }
}

// ---------------- K3fat: local bucketing + incremental bases + scan + emit ----------------
// grid = B*NG = 256 blocks, 256 threads. Block (b,g) owns chunks 4g..4g+3.
__global__ __launch_bounds__(256)
void k3fat(const float* __restrict__ h, const float* __restrict__ keys,
           const int* __restrict__ sidx, const float* __restrict__ si,
           const float* __restrict__ ew1, const float* __restrict__ ew2,
           const float* __restrict__ csum1, const float* __restrict__ csum2,
           const float* __restrict__ ssum1, const float* __restrict__ ssum2,
           float* __restrict__ out)
{
    __shared__ float hs[CH][FF];            // 8 KB
    __shared__ float S1pos[CH + 1][FF];     // 8.7 KB
    __shared__ float P2pos[CH + 1][FF];     // 8.7 KB
    __shared__ float bS1[FF], bP2[FF];      // running vector bases
    __shared__ float lw1[CH], lw2[CH], lkey[CH];
    __shared__ float T1pos[CH + 1], T2pos[CH + 1];
    __shared__ float ls1[NCH], ls2[NCH];
    __shared__ float bp1[2][FF], bp2[2][FF];
    __shared__ float bk[5];
    __shared__ float tb1[GC], tb2[GC];
    __shared__ int lcnt[GC];
    __shared__ int lrows[GC][256];          // 4 KB

    const int bid = blockIdx.x;
    const int b = bid >> 5, g = bid & (NG - 1);
    const int t = threadIdx.x;
    const int o = t & 127, ht = t >> 7;
    const int c0 = g * GC;

    // stage scalar sums, boundary keys, zero counts
    if (ht == 0) ls1[o] = ssum1[b * NCH + o];
    else         ls2[o] = ssum2[b * NCH + o];
    if (t < GC) lcnt[t] = 0;
    if (t < 5) {
        int idx = (c0 + t) * CH;
        bk[t] = (idx < NN) ? keys[b * NN + idx] : 0.f;   // t==4 unused when g==31
    }
    __syncthreads();

    // local bucketing: 8 coalesced si reads per thread
    {
        const float bk0 = bk[0], bk1 = bk[1], bk2 = bk[2], bk3 = bk[3], bk4 = bk[4];
        for (int k = 0; k < 8; ++k) {
            int i = (k << 8) + t;
            float thr = -si[b * NN + i];
            bool ge = (g == 0) || (bk0 < thr);
            bool lt = (g == NG - 1) || !(bk4 < thr);
            if (ge && lt) {
                int cc = (bk1 < thr) + (bk2 < thr) + (bk3 < thr);
                int pos = atomicAdd(&lcnt[cc], 1);
                if (pos < 256) lrows[cc][pos] = i;
            }
        }
    }

    // initial vector bases for chunk c0 (balanced halves)
    {
        const int c2lo = ht << 6, c2hi = c2lo + 64;
        float a1 = 0.f, a2 = 0.f;
        const int lo1 = (c0 + 1 > c2lo) ? c0 + 1 : c2lo;
#pragma unroll 8
        for (int c2 = lo1; c2 < c2hi; ++c2)
            a1 += csum1[(size_t)(b * NCH + c2) * FF + o];
        const int hi2 = (c0 < c2hi) ? c0 : c2hi;
#pragma unroll 8
        for (int c2 = c2lo; c2 < hi2; ++c2)
            a2 += csum2[(size_t)(b * NCH + c2) * FF + o];
        bp1[ht][o] = a1;
        bp2[ht][o] = a2;
    }
    // scalar bases per chunk (8 parallel lanes; reads ls* staged pre-sync)
    if (t < GC) {
        float s = 0.f;
        for (int c2 = c0 + t + 1; c2 < NCH; ++c2) s += ls1[c2];
        tb1[t] = s;
    } else if (t < 2 * GC) {
        const int cc = t - GC;
        float s = 0.f;
        for (int c2 = 0; c2 < c0 + cc; ++c2) s += ls2[c2];
        tb2[cc] = s;
    }
    __syncthreads();
    if (ht == 0) bS1[o] = bp1[0][o] + bp1[1][o];
    else         bP2[o] = bp2[0][o] + bp2[1][o];

    // chunk loop
    for (int cc = 0; cc < GC; ++cc) {
        const int c = c0 + cc;
        const int m0 = c * CH;
        __syncthreads();                       // prev emit done before restaging
        if (t < CH) {
            lkey[t] = keys[b * NN + m0 + t];
            lw1[t]  = ew1[b * NN + m0 + t];
            lw2[t]  = ew2[b * NN + m0 + t];
        }
        for (int kk = t; kk < CH * FF; kk += 256) {
            int m = kk >> 7, f = kk & 127;
            hs[m][f] = h[(size_t)(b * NN + sidx[b * NN + m0 + m]) * FF + f];
        }
        __syncthreads();

        if (ht == 0) {
            float s = bS1[o];
            S1pos[CH][o] = s;
#pragma unroll
            for (int m = CH - 1; m >= 0; --m) { s += lw1[m] * hs[m][o]; S1pos[m][o] = s; }
            if (t < CH + 1) {
                float ts = tb1[cc];
                for (int mm = CH - 1; mm >= t; --mm) ts += lw1[mm];
                T1pos[t] = ts;
            }
        } else {
            float s = bP2[o];
            P2pos[0][o] = s;
#pragma unroll
            for (int m = 0; m < CH; ++m) { s += lw2[m] * hs[m][o]; P2pos[m + 1][o] = s; }
            if (o < CH + 1) {
                float ts = tb2[cc];
                for (int mm = 0; mm < o; ++mm) ts += lw2[mm];
                T2pos[o] = ts;
            }
        }
        __syncthreads();

        // emit bucket cc
        int nrows = lcnt[cc]; if (nrows > 256) nrows = 256;
        for (int r0 = 0; r0 < nrows; r0 += 2) {
            const int ri = r0 + ht;
            if (ri < nrows) {
                const int i = lrows[cc][ri];
                const float siv = si[b * NN + i];
                const float thr = -siv;
                int rel = 0;
#pragma unroll
                for (int m = 0; m < CH; ++m) rel += (lkey[m] < thr);
                const float e1 = expf(siv), e2 = expf(LALPHA * siv);
                const float num = e1 * S1pos[rel][o] + e2 * P2pos[rel][o];
                const float den = e1 * T1pos[rel] + e2 * T2pos[rel];
                out[(size_t)(b * NN + i) * FF + o] = num / den;
            }
        }

        // advance bases (reads: csum1 next row / local P2pos; no conflict with emit reads)
        if (cc < GC - 1) {
            if (ht == 0) bS1[o] -= csum1[(size_t)(b * NCH + c + 1) * FF + o];
            else         bP2[o] = P2pos[CH][o];
        }
    }
}

extern "C" void kernel_launch(void* const* d_in, const int* in_sizes, int n_in,
                              void* d_out, int out_size, void* d_ws, size_t ws_size,
                              hipStream_t stream)
{
    const float* x = (const float*)d_in[0];
    const float* W = (const float*)d_in[1];
    const float* a = (const float*)d_in[2];
    float* out = (float*)d_out;

    float* ws = (float*)d_ws;
    float* h     = ws;                           // B*N*F
    float* si    = h + BB * NN * FF;             // B*N
    float* sj    = si + BB * NN;                 // B*N
    float* keys  = sj + BB * NN;                 // B*N
    int*   sidx  = (int*)(keys + BB * NN);       // B*N
    float* ew1   = (float*)(sidx + BB * NN);     // B*N
    float* ew2   = ew1 + BB * NN;                // B*N
    float* csum1 = ew2 + BB * NN;                // B*NCH*F
    float* csum2 = csum1 + BB * NCH * FF;        // B*NCH*F
    float* ssum1 = csum2 + BB * NCH * FF;        // B*NCH
    float* ssum2 = ssum1 + BB * NCH;             // B*NCH

    hipLaunchKernelGGL(k1_h, dim3(BB * NN / K1R), dim3(256), 0, stream, x, W, a, h, si, sj);
    hipLaunchKernelGGL(k2_rank, dim3(BB * 32), dim3(1024), 0, stream, sj, keys, sidx, ew1, ew2);
    hipLaunchKernelGGL(k3a_csum, dim3(BB * NCH), dim3(128), 0, stream,
                       h, sidx, ew1, ew2, csum1, csum2, ssum1, ssum2);
    hipLaunchKernelGGL(k3fat, dim3(BB * NG), dim3(256), 0, stream,
                       h, keys, sidx, si, ew1, ew2, csum1, csum2, ssum1, ssum2, out);
}

// Round 12
// 56.676 us; speedup vs baseline: 1.3745x; 1.3745x over previous
//
#include <hip/hip_runtime.h>
#include <math.h>

#define BB 8
#define NN 2048
#define FF 128
#define LALPHA 0.2f
#define CH 16
#define NCH (NN / CH)     // 128

// ---------------- K1: h = x @ W^T, si = h.a1, sj = h.a2 (+ zero cnt) ----------------
// 512 blocks (2/CU) x 256 threads; 32 rows x 128 cols; thread tile 2x8.
// W in LDS (67.6 KB, 2 blocks/CU = 135 KB <= 160); x direct from global (L1).
#define K1R 32
__global__ __launch_bounds__(256, 2)
void k1_h(const float* __restrict__ x, const float* __restrict__ W,
          const float* __restrict__ a, float* __restrict__ h,
          float* __restrict__ si, float* __restrict__ sj, int* __restrict__ cnt)
{
    __shared__ float Wt[FF * 132];
    const int t = threadIdx.x;
    const int row0 = blockIdx.x * K1R;

    if (blockIdx.x == 0)
        for (int kk = t; kk < BB * NCH; kk += 256) cnt[kk] = 0;

    for (int kk = t; kk < FF * FF; kk += 256) {
        int o = kk >> 7, f = kk & (FF - 1);
        Wt[f * 132 + o] = W[kk];
    }
    __syncthreads();

    const int tx = t & 15, ty = t >> 4;
    const int oq = tx << 3;           // 8 cols
    const int rq = ty << 1;           // 2 rows
    float acc[2][8];
#pragma unroll
    for (int r = 0; r < 2; ++r)
#pragma unroll
        for (int c = 0; c < 8; ++c) acc[r][c] = 0.f;

    for (int f0 = 0; f0 < FF; f0 += 4) {
        float4 xv[2];
#pragma unroll
        for (int r = 0; r < 2; ++r)
            xv[r] = *(const float4*)&x[(size_t)(row0 + rq + r) * FF + f0];
#pragma unroll
        for (int ff = 0; ff < 4; ++ff) {
            float4 w0 = *(const float4*)&Wt[(f0 + ff) * 132 + oq];
            float4 w1 = *(const float4*)&Wt[(f0 + ff) * 132 + oq + 4];
            const float wc[8] = {w0.x, w0.y, w0.z, w0.w, w1.x, w1.y, w1.z, w1.w};
#pragma unroll
            for (int r = 0; r < 2; ++r) {
                const float xr = (ff == 0) ? xv[r].x : (ff == 1) ? xv[r].y
                               : (ff == 2) ? xv[r].z : xv[r].w;
#pragma unroll
                for (int c = 0; c < 8; ++c)
                    acc[r][c] += xr * wc[c];
            }
        }
    }
#pragma unroll
    for (int r = 0; r < 2; ++r) {
        float* hp = &h[(size_t)(row0 + rq + r) * FF + oq];
        *(float4*)hp       = make_float4(acc[r][0], acc[r][1], acc[r][2], acc[r][3]);
        *(float4*)(hp + 4) = make_float4(acc[r][4], acc[r][5], acc[r][6], acc[r][7]);
    }
    const float4 a10 = *(const float4*)&a[oq];
    const float4 a11 = *(const float4*)&a[oq + 4];
    const float4 a20 = *(const float4*)&a[FF + oq];
    const float4 a21 = *(const float4*)&a[FF + oq + 4];
    const float a1v[8] = {a10.x, a10.y, a10.z, a10.w, a11.x, a11.y, a11.z, a11.w};
    const float a2v[8] = {a20.x, a20.y, a20.z, a20.w, a21.x, a21.y, a21.z, a21.w};
#pragma unroll
    for (int r = 0; r < 2; ++r) {
        float s1 = 0.f, s2 = 0.f;
#pragma unroll
        for (int c = 0; c < 8; ++c) { s1 += acc[r][c] * a1v[c]; s2 += acc[r][c] * a2v[c]; }
#pragma unroll
        for (int off = 8; off >= 1; off >>= 1) {
            s1 += __shfl_down(s1, off, 16);
            s2 += __shfl_down(s2, off, 16);
        }
        if (tx == 0) { si[row0 + rq + r] = s1; sj[row0 + rq + r] = s2; }
    }
}

// ---------------- K2: rank-sort sj per batch (+ exp weights) ----------------
// grid = B*32 = 256 blocks, 1024 threads; 16 slices per element.
__global__ __launch_bounds__(1024)
void k2_rank(const float* __restrict__ sj, float* __restrict__ keys, int* __restrict__ sidx,
             float* __restrict__ ew1, float* __restrict__ ew2)
{
    __shared__ float lk[NN];
    const int b = blockIdx.x >> 5;
    const int s = blockIdx.x & 31;
    const int t = threadIdx.x;
    for (int j = t; j < NN; j += 1024) lk[j] = sj[b * NN + j];
    __syncthreads();
    const int e = s * 64 + (t >> 4);
    const int slice = t & 15;
    const float ki = lk[e];
    const float4* lk4 = (const float4*)lk;
    int r = 0;
#pragma unroll 8
    for (int it = 0; it < 32; ++it) {
        int q = slice + (it << 4);
        float4 v = lk4[q];
        int j = q << 2;
        r += (v.x < ki || (v.x == ki && (j + 0) < e));
        r += (v.y < ki || (v.y == ki && (j + 1) < e));
        r += (v.z < ki || (v.z == ki && (j + 2) < e));
        r += (v.w < ki || (v.w == ki && (j + 3) < e));
    }
    r += __shfl_down(r, 8, 16);
    r += __shfl_down(r, 4, 16);
    r += __shfl_down(r, 2, 16);
    r += __shfl_down(r, 1, 16);
    if (slice == 0) {
        keys[b * NN + r] = ki;
        sidx[b * NN + r] = e;
        ew1[b * NN + r] = expf(ki);
        ew2[b * NN + r] = expf(LALPHA * ki);
    }
}

// ---------------- K3a: chunk sums + row bucketing ----------------
__global__ __launch_bounds__(128)
void k3a_csum(const float* __restrict__ h, const float* __restrict__ keys,
              const int* __restrict__ sidx, const float* __restrict__ si,
              const float* __restrict__ ew1, const float* __restrict__ ew2,
              float* __restrict__ csum1, float* __restrict__ csum2,
              float* __restrict__ ssum1, float* __restrict__ ssum2,
              int* __restrict__ cnt, int* __restrict__ brows)
{
    const int bid = blockIdx.x;
    const int b = bid >> 7, c = bid & (NCH - 1);
    const int o = threadIdx.x;
    const int m0 = c * CH;

    __shared__ float lw1[CH], lw2[CH];
    __shared__ int li[CH];
    __shared__ float bkey[NCH];
    if (o < CH) {
        lw1[o] = ew1[b * NN + m0 + o];
        lw2[o] = ew2[b * NN + m0 + o];
        li[o]  = sidx[b * NN + m0 + o];
    }
    bkey[o] = keys[b * NN + (o << 4)];
    __syncthreads();

    float r[CH];
#pragma unroll
    for (int m = 0; m < CH; ++m)
        r[m] = h[(size_t)(b * NN + li[m]) * FF + o];

    float a1 = 0.f, a2 = 0.f, s1 = 0.f, s2 = 0.f;
#pragma unroll
    for (int m = 0; m < CH; ++m) {
        float w1 = lw1[m], w2 = lw2[m];
        a1 += w1 * r[m]; a2 += w2 * r[m];
        s1 += w1;        s2 += w2;
    }
    csum1[(size_t)bid * FF + o] = a1;
    csum2[(size_t)bid * FF + o] = a2;
    if (o == 0) { ssum1[bid] = s1; ssum2[bid] = s2; }

    // bucket rows m0..m0+15 (ORIGINAL indices) by chunk of their partition point
    const int rl = o >> 3, slice = o & 7;
    const int i = m0 + rl;
    const float thr = -si[b * NN + i];
    int cc = 0;
#pragma unroll
    for (int k = 0; k < 16; ++k) {
        int c2 = slice * 16 + k;
        cc += (c2 >= 1) && (bkey[c2] < thr);
    }
    cc += __shfl_down(cc, 4, 8);
    cc += __shfl_down(cc, 2, 8);
    cc += __shfl_down(cc, 1, 8);
    if (slice == 0) {
        int pos = atomicAdd(&cnt[b * NCH + cc], 1);
        brows[(size_t)(b * NCH + cc) * NN + pos] = i;
    }
}

// ---------------- K3se: balanced bases + in-LDS scan + direct emit ----------------
// grid = B*NCH = 1024 blocks, 256 threads (2 halves of 128).
__global__ __launch_bounds__(256)
void k3se_emit(const float* __restrict__ h, const float* __restrict__ keys,
               const int* __restrict__ sidx, const float* __restrict__ si,
               const float* __restrict__ ew1, const float* __restrict__ ew2,
               const float* __restrict__ csum1, const float* __restrict__ csum2,
               const float* __restrict__ ssum1, const float* __restrict__ ssum2,
               const int* __restrict__ cnt, const int* __restrict__ brows,
               float* __restrict__ out)
{
    __shared__ float hs[CH][FF];            // 8 KB
    __shared__ float S1pos[CH + 1][FF];     // 8.7 KB
    __shared__ float P2pos[CH + 1][FF];     // 8.7 KB
    __shared__ float lw1[CH], lw2[CH], lkey[CH];
    __shared__ float T1pos[CH + 1], T2pos[CH + 1];
    __shared__ float ls1[NCH], ls2[NCH];    // staged scalar sums
    __shared__ float bp1[2][FF], bp2[2][FF];

    const int bid = blockIdx.x;
    const int b = bid >> 7, c = bid & (NCH - 1);
    const int t = threadIdx.x;
    const int o = t & 127, ht = t >> 7;
    const int m0 = c * CH;

    if (t < CH) {
        lkey[t] = keys[b * NN + m0 + t];
        lw1[t]  = ew1[b * NN + m0 + t];
        lw2[t]  = ew2[b * NN + m0 + t];
    }
    if (ht == 0) ls1[o] = ssum1[b * NCH + o];
    else         ls2[o] = ssum2[b * NCH + o];

    // stage hs: preload the 8 sidx values (independent), then 8 independent gathers
    {
        int sid[8];
#pragma unroll
        for (int it = 0; it < 8; ++it) {
            int kk = t + (it << 8);
            sid[it] = sidx[b * NN + m0 + (kk >> 7)];
        }
#pragma unroll
        for (int it = 0; it < 8; ++it) {
            int kk = t + (it << 8);
            hs[kk >> 7][kk & 127] = h[(size_t)(b * NN + sid[it]) * FF + (kk & 127)];
        }
    }

    // balanced vector bases: thread (o, ht) covers c2 in [ht*64, ht*64+64)
    {
        const int c2lo = ht << 6, c2hi = c2lo + 64;
        float a1 = 0.f, a2 = 0.f;
        const int lo1 = (c + 1 > c2lo) ? c + 1 : c2lo;   // suffix side (csum1)
#pragma unroll 8
        for (int c2 = lo1; c2 < c2hi; ++c2)
            a1 += csum1[(size_t)(b * NCH + c2) * FF + o];
        const int hi2 = (c < c2hi) ? c : c2hi;           // prefix side (csum2)
#pragma unroll 8
        for (int c2 = c2lo; c2 < hi2; ++c2)
            a2 += csum2[(size_t)(b * NCH + c2) * FF + o];
        bp1[ht][o] = a1;
        bp2[ht][o] = a2;
    }
    __syncthreads();

    // vector scans (halves) + parallel scalar T (16 lanes each side)
    if (ht == 0) {
        float s = bp1[0][o] + bp1[1][o];
        S1pos[CH][o] = s;
#pragma unroll
        for (int m = CH - 1; m >= 0; --m) {
            s += lw1[m] * hs[m][o];
            S1pos[m][o] = s;
        }
        if (t < CH + 1) {
            float ts = 0.f;
#pragma unroll 8
            for (int c2 = c + 1; c2 < NCH; ++c2) ts += ls1[c2];
            for (int mm = CH - 1; mm >= t; --mm) ts += lw1[mm];
            T1pos[t] = ts;
        }
    } else {
        float s = bp2[0][o] + bp2[1][o];
        P2pos[0][o] = s;
#pragma unroll
        for (int m = 0; m < CH; ++m) {
            s += lw2[m] * hs[m][o];
            P2pos[m + 1][o] = s;
        }
        if (o < CH + 1) {
            float ts = 0.f;
#pragma unroll 8
            for (int c2 = 0; c2 < c; ++c2) ts += ls2[c2];
            for (int mm = 0; mm < o; ++mm) ts += lw2[mm];
            T2pos[o] = ts;
        }
    }
    __syncthreads();

    const int nrows = cnt[b * NCH + c];
    const int* br = brows + (size_t)(b * NCH + c) * NN;

    for (int r0 = 0; r0 < nrows; r0 += 2) {
        const int ri = r0 + ht;
        if (ri < nrows) {
            const int i = br[ri];
            const float siv = si[b * NN + i];
            const float thr = -siv;
            int rel = 0;
#pragma unroll
            for (int m = 0; m < CH; ++m) rel += (lkey[m] < thr);
            const float e1 = expf(siv), e2 = expf(LALPHA * siv);
            const float num = e1 * S1pos[rel][o] + e2 * P2pos[rel][o];
            const float den = e1 * T1pos[rel] + e2 * T2pos[rel];
            out[(size_t)(b * NN + i) * FF + o] = num / den;
        }
    }
}

extern "C" void kernel_launch(void* const* d_in, const int* in_sizes, int n_in,
                              void* d_out, int out_size, void* d_ws, size_t ws_size,
                              hipStream_t stream)
{
    const float* x = (const float*)d_in[0];
    const float* W = (const float*)d_in[1];
    const float* a = (const float*)d_in[2];
    float* out = (float*)d_out;

    float* ws = (float*)d_ws;
    float* h     = ws;                           // B*N*F
    float* si    = h + BB * NN * FF;             // B*N
    float* sj    = si + BB * NN;                 // B*N
    float* keys  = sj + BB * NN;                 // B*N
    int*   sidx  = (int*)(keys + BB * NN);       // B*N
    float* ew1   = (float*)(sidx + BB * NN);     // B*N
    float* ew2   = ew1 + BB * NN;                // B*N
    float* csum1 = ew2 + BB * NN;                // B*NCH*F
    float* csum2 = csum1 + BB * NCH * FF;        // B*NCH*F
    float* ssum1 = csum2 + BB * NCH * FF;        // B*NCH
    float* ssum2 = ssum1 + BB * NCH;             // B*NCH
    int*   cnt   = (int*)(ssum2 + BB * NCH);     // B*NCH
    int*   brows = cnt + BB * NCH;               // B*NCH*N (8.4 MB)

    hipLaunchKernelGGL(k1_h, dim3(BB * NN / K1R), dim3(256), 0, stream, x, W, a, h, si, sj, cnt);
    hipLaunchKernelGGL(k2_rank, dim3(BB * 32), dim3(1024), 0, stream, sj, keys, sidx, ew1, ew2);
    hipLaunchKernelGGL(k3a_csum, dim3(BB * NCH), dim3(128), 0, stream,
                       h, keys, sidx, si, ew1, ew2, csum1, csum2, ssum1, ssum2, cnt, brows);
    hipLaunchKernelGGL(k3se_emit, dim3(BB * NCH), dim3(256), 0, stream,
                       h, keys, sidx, si, ew1, ew2, csum1, csum2, ssum1, ssum2, cnt, brows, out);
}

// Round 13
// 53.602 us; speedup vs baseline: 1.4533x; 1.0573x over previous
//
#include <hip/hip_runtime.h>
#include <math.h>

#define BB 8
#define NN 2048
#define FF 128
#define LALPHA 0.2f
#define CH 16
#define NCH (NN / CH)     // 128

// ---------------- K1: h = x @ W^T, si = h.a1, sj = h.a2 ----------------
// 512 blocks (2/CU) x 256 threads; 32 rows x 128 cols; thread tile 2x8.
// W in LDS (67.6 KB); x direct from global (L1 broadcast).
#define K1R 32
__global__ __launch_bounds__(256, 2)
void k1_h(const float* __restrict__ x, const float* __restrict__ W,
          const float* __restrict__ a, float* __restrict__ h,
          float* __restrict__ si, float* __restrict__ sj)
{
    __shared__ float Wt[FF * 132];
    const int t = threadIdx.x;
    const int row0 = blockIdx.x * K1R;

    for (int kk = t; kk < FF * FF; kk += 256) {
        int o = kk >> 7, f = kk & (FF - 1);
        Wt[f * 132 + o] = W[kk];
    }
    __syncthreads();

    const int tx = t & 15, ty = t >> 4;
    const int oq = tx << 3;           // 8 cols
    const int rq = ty << 1;           // 2 rows
    float acc[2][8];
#pragma unroll
    for (int r = 0; r < 2; ++r)
#pragma unroll
        for (int c = 0; c < 8; ++c) acc[r][c] = 0.f;

    for (int f0 = 0; f0 < FF; f0 += 4) {
        float4 xv[2];
#pragma unroll
        for (int r = 0; r < 2; ++r)
            xv[r] = *(const float4*)&x[(size_t)(row0 + rq + r) * FF + f0];
#pragma unroll
        for (int ff = 0; ff < 4; ++ff) {
            float4 w0 = *(const float4*)&Wt[(f0 + ff) * 132 + oq];
            float4 w1 = *(const float4*)&Wt[(f0 + ff) * 132 + oq + 4];
            const float wc[8] = {w0.x, w0.y, w0.z, w0.w, w1.x, w1.y, w1.z, w1.w};
#pragma unroll
            for (int r = 0; r < 2; ++r) {
                const float xr = (ff == 0) ? xv[r].x : (ff == 1) ? xv[r].y
                               : (ff == 2) ? xv[r].z : xv[r].w;
#pragma unroll
                for (int c = 0; c < 8; ++c)
                    acc[r][c] += xr * wc[c];
            }
        }
    }
#pragma unroll
    for (int r = 0; r < 2; ++r) {
        float* hp = &h[(size_t)(row0 + rq + r) * FF + oq];
        *(float4*)hp       = make_float4(acc[r][0], acc[r][1], acc[r][2], acc[r][3]);
        *(float4*)(hp + 4) = make_float4(acc[r][4], acc[r][5], acc[r][6], acc[r][7]);
    }
    const float4 a10 = *(const float4*)&a[oq];
    const float4 a11 = *(const float4*)&a[oq + 4];
    const float4 a20 = *(const float4*)&a[FF + oq];
    const float4 a21 = *(const float4*)&a[FF + oq + 4];
    const float a1v[8] = {a10.x, a10.y, a10.z, a10.w, a11.x, a11.y, a11.z, a11.w};
    const float a2v[8] = {a20.x, a20.y, a20.z, a20.w, a21.x, a21.y, a21.z, a21.w};
#pragma unroll
    for (int r = 0; r < 2; ++r) {
        float s1 = 0.f, s2 = 0.f;
#pragma unroll
        for (int c = 0; c < 8; ++c) { s1 += acc[r][c] * a1v[c]; s2 += acc[r][c] * a2v[c]; }
#pragma unroll
        for (int off = 8; off >= 1; off >>= 1) {
            s1 += __shfl_down(s1, off, 16);
            s2 += __shfl_down(s2, off, 16);
        }
        if (tx == 0) { si[row0 + rq + r] = s1; sj[row0 + rq + r] = s2; }
    }
}

// ---------------- K2: rank-sort sj per batch (+ exp weights) ----------------
// grid = B*32 = 256 blocks, 1024 threads; 16 slices per element.
__global__ __launch_bounds__(1024)
void k2_rank(const float* __restrict__ sj, float* __restrict__ keys, int* __restrict__ sidx,
             float* __restrict__ ew1, float* __restrict__ ew2)
{
    __shared__ float lk[NN];
    const int b = blockIdx.x >> 5;
    const int s = blockIdx.x & 31;
    const int t = threadIdx.x;
    for (int j = t; j < NN; j += 1024) lk[j] = sj[b * NN + j];
    __syncthreads();
    const int e = s * 64 + (t >> 4);
    const int slice = t & 15;
    const float ki = lk[e];
    const float4* lk4 = (const float4*)lk;
    int r = 0;
#pragma unroll 8
    for (int it = 0; it < 32; ++it) {
        int q = slice + (it << 4);
        float4 v = lk4[q];
        int j = q << 2;
        r += (v.x < ki || (v.x == ki && (j + 0) < e));
        r += (v.y < ki || (v.y == ki && (j + 1) < e));
        r += (v.z < ki || (v.z == ki && (j + 2) < e));
        r += (v.w < ki || (v.w == ki && (j + 3) < e));
    }
    r += __shfl_down(r, 8, 16);
    r += __shfl_down(r, 4, 16);
    r += __shfl_down(r, 2, 16);
    r += __shfl_down(r, 1, 16);
    if (slice == 0) {
        keys[b * NN + r] = ki;
        sidx[b * NN + r] = e;
        ew1[b * NN + r] = expf(ki);
        ew2[b * NN + r] = expf(LALPHA * ki);
    }
}

// ---------------- K3a: chunk sums only ----------------
// grid = B*NCH = 1024 blocks, 128 threads.
__global__ __launch_bounds__(128)
void k3a_csum(const float* __restrict__ h, const int* __restrict__ sidx,
              const float* __restrict__ ew1, const float* __restrict__ ew2,
              float* __restrict__ csum1, float* __restrict__ csum2,
              float* __restrict__ ssum1, float* __restrict__ ssum2)
{
    const int bid = blockIdx.x;
    const int b = bid >> 7, c = bid & (NCH - 1);
    const int o = threadIdx.x;
    const int m0 = c * CH;

    __shared__ float lw1[CH], lw2[CH];
    __shared__ int li[CH];
    if (o < CH) {
        lw1[o] = ew1[b * NN + m0 + o];
        lw2[o] = ew2[b * NN + m0 + o];
        li[o]  = sidx[b * NN + m0 + o];
    }
    __syncthreads();

    float r[CH];
#pragma unroll
    for (int m = 0; m < CH; ++m)
        r[m] = h[(size_t)(b * NN + li[m]) * FF + o];

    float a1 = 0.f, a2 = 0.f, s1 = 0.f, s2 = 0.f;
#pragma unroll
    for (int m = 0; m < CH; ++m) {
        float w1 = lw1[m], w2 = lw2[m];
        a1 += w1 * r[m]; a2 += w2 * r[m];
        s1 += w1;        s2 += w2;
    }
    csum1[(size_t)bid * FF + o] = a1;
    csum2[(size_t)bid * FF + o] = a2;
    if (o == 0) { ssum1[bid] = s1; ssum2[bid] = s2; }
}

// ---------------- K3se: local bucketing + balanced bases + in-LDS scan + emit ----------------
// grid = B*NCH = 1024 blocks, 256 threads (2 halves of 128).
// Sorted keys => bucket test is local: row i in chunk c iff
//   (c==0 || keys[16c] < -si[i]) && (c==NCH-1 || keys[16(c+1)] >= -si[i]).
__global__ __launch_bounds__(256)
void k3se_emit(const float* __restrict__ h, const float* __restrict__ keys,
               const int* __restrict__ sidx, const float* __restrict__ si,
               const float* __restrict__ ew1, const float* __restrict__ ew2,
               const float* __restrict__ csum1, const float* __restrict__ csum2,
               const float* __restrict__ ssum1, const float* __restrict__ ssum2,
               float* __restrict__ out)
{
    __shared__ float hs[CH][FF];            // 8 KB
    __shared__ float S1pos[CH + 1][FF];     // 8.7 KB
    __shared__ float P2pos[CH + 1][FF];     // 8.7 KB
    __shared__ float lw1[CH], lw2[CH], lkey[CH];
    __shared__ float T1pos[CH + 1], T2pos[CH + 1];
    __shared__ float ls1[NCH], ls2[NCH];    // staged scalar sums
    __shared__ float bp1[2][FF], bp2[2][FF];
    __shared__ int lcnt;
    __shared__ int lrows[256];              // 1 KB bucket list (avg 16, max ~40)

    const int bid = blockIdx.x;
    const int b = bid >> 7, c = bid & (NCH - 1);
    const int t = threadIdx.x;
    const int o = t & 127, ht = t >> 7;
    const int m0 = c * CH;

    if (t == 0) lcnt = 0;
    if (t < CH) {
        lkey[t] = keys[b * NN + m0 + t];
        lw1[t]  = ew1[b * NN + m0 + t];
        lw2[t]  = ew2[b * NN + m0 + t];
    }
    if (ht == 0) ls1[o] = ssum1[b * NCH + o];
    else         ls2[o] = ssum2[b * NCH + o];

    // stage hs: preload the 8 sidx values (independent), then 8 independent gathers
    {
        int sid[8];
#pragma unroll
        for (int it = 0; it < 8; ++it) {
            int kk = t + (it << 8);
            sid[it] = sidx[b * NN + m0 + (kk >> 7)];
        }
#pragma unroll
        for (int it = 0; it < 8; ++it) {
            int kk = t + (it << 8);
            hs[kk >> 7][kk & 127] = h[(size_t)(b * NN + sid[it]) * FF + (kk & 127)];
        }
    }

    // balanced vector bases: thread (o, ht) covers c2 in [ht*64, ht*64+64)
    {
        const int c2lo = ht << 6, c2hi = c2lo + 64;
        float a1 = 0.f, a2 = 0.f;
        const int lo1 = (c + 1 > c2lo) ? c + 1 : c2lo;   // suffix side (csum1)
#pragma unroll 8
        for (int c2 = lo1; c2 < c2hi; ++c2)
            a1 += csum1[(size_t)(b * NCH + c2) * FF + o];
        const int hi2 = (c < c2hi) ? c : c2hi;           // prefix side (csum2)
#pragma unroll 8
        for (int c2 = c2lo; c2 < hi2; ++c2)
            a2 += csum2[(size_t)(b * NCH + c2) * FF + o];
        bp1[ht][o] = a1;
        bp2[ht][o] = a2;
    }
    __syncthreads();

    // local bucketing: broadcast boundary keys, 8 coalesced si reads per thread
    {
        const float bk0 = keys[b * NN + m0];                                  // lower boundary
        const float bk1 = (c < NCH - 1) ? keys[b * NN + m0 + CH] : 0.f;       // upper boundary
        for (int k = 0; k < 8; ++k) {
            int i = (k << 8) + t;
            float thr = -si[b * NN + i];
            bool ge = (c == 0) || (bk0 < thr);
            bool lt = (c == NCH - 1) || !(bk1 < thr);
            if (ge && lt) {
                int pos = atomicAdd(&lcnt, 1);
                if (pos < 256) lrows[pos] = i;
            }
        }
    }

    // vector scans (halves) + parallel scalar T (16 lanes each side)
    if (ht == 0) {
        float s = bp1[0][o] + bp1[1][o];
        S1pos[CH][o] = s;
#pragma unroll
        for (int m = CH - 1; m >= 0; --m) {
            s += lw1[m] * hs[m][o];
            S1pos[m][o] = s;
        }
        if (t < CH + 1) {
            float ts = 0.f;
#pragma unroll 8
            for (int c2 = c + 1; c2 < NCH; ++c2) ts += ls1[c2];
            for (int mm = CH - 1; mm >= t; --mm) ts += lw1[mm];
            T1pos[t] = ts;
        }
    } else {
        float s = bp2[0][o] + bp2[1][o];
        P2pos[0][o] = s;
#pragma unroll
        for (int m = 0; m < CH; ++m) {
            s += lw2[m] * hs[m][o];
            P2pos[m + 1][o] = s;
        }
        if (o < CH + 1) {
            float ts = 0.f;
#pragma unroll 8
            for (int c2 = 0; c2 < c; ++c2) ts += ls2[c2];
            for (int mm = 0; mm < o; ++mm) ts += lw2[mm];
            T2pos[o] = ts;
        }
    }
    __syncthreads();

    int nrows = lcnt; if (nrows > 256) nrows = 256;
    for (int r0 = 0; r0 < nrows; r0 += 2) {
        const int ri = r0 + ht;
        if (ri < nrows) {
            const int i = lrows[ri];
            const float siv = si[b * NN + i];
            const float thr = -siv;
            int rel = 0;
#pragma unroll
            for (int m = 0; m < CH; ++m) rel += (lkey[m] < thr);
            const float e1 = expf(siv), e2 = expf(LALPHA * siv);
            const float num = e1 * S1pos[rel][o] + e2 * P2pos[rel][o];
            const float den = e1 * T1pos[rel] + e2 * T2pos[rel];
            out[(size_t)(b * NN + i) * FF + o] = num / den;
        }
    }
}

extern "C" void kernel_launch(void* const* d_in, const int* in_sizes, int n_in,
                              void* d_out, int out_size, void* d_ws, size_t ws_size,
                              hipStream_t stream)
{
    const float* x = (const float*)d_in[0];
    const float* W = (const float*)d_in[1];
    const float* a = (const float*)d_in[2];
    float* out = (float*)d_out;

    float* ws = (float*)d_ws;
    float* h     = ws;                           // B*N*F
    float* si    = h + BB * NN * FF;             // B*N
    float* sj    = si + BB * NN;                 // B*N
    float* keys  = sj + BB * NN;                 // B*N
    int*   sidx  = (int*)(keys + BB * NN);       // B*N
    float* ew1   = (float*)(sidx + BB * NN);     // B*N
    float* ew2   = ew1 + BB * NN;                // B*N
    float* csum1 = ew2 + BB * NN;                // B*NCH*F
    float* csum2 = csum1 + BB * NCH * FF;        // B*NCH*F
    float* ssum1 = csum2 + BB * NCH * FF;        // B*NCH
    float* ssum2 = ssum1 + BB * NCH;             // B*NCH

    hipLaunchKernelGGL(k1_h, dim3(BB * NN / K1R), dim3(256), 0, stream, x, W, a, h, si, sj);
    hipLaunchKernelGGL(k2_rank, dim3(BB * 32), dim3(1024), 0, stream, sj, keys, sidx, ew1, ew2);
    hipLaunchKernelGGL(k3a_csum, dim3(BB * NCH), dim3(128), 0, stream,
                       h, sidx, ew1, ew2, csum1, csum2, ssum1, ssum2);
    hipLaunchKernelGGL(k3se_emit, dim3(BB * NCH), dim3(256), 0, stream,
                       h, keys, sidx, si, ew1, ew2, csum1, csum2, ssum1, ssum2, out);
}